// Round 4
// baseline (1680.926 us; speedup 1.0000x reference)
//
#include <hip/hip_runtime.h>
#include <stdint.h>

#define K_DIM 4096
#define N_DIM 11008
#define M_DIM 8192
#define BM 128
#define BN 128
#define BK 32
#define NSLAB (K_DIM / BK)    // 128

typedef _Float16 half8   __attribute__((ext_vector_type(8)));
typedef _Float16 half2v  __attribute__((ext_vector_type(2)));
typedef float    floatx4 __attribute__((ext_vector_type(4)));

#define WS_X16_BYTES  ((size_t)M_DIM * K_DIM * 2)            // 67,108,864
#define WS_W16_BYTES  ((size_t)N_DIM * K_DIM * 2)            // 90,177,536
#define WS_NEEDED     (WS_X16_BYTES + WS_W16_BYTES)

__device__ __forceinline__ void async_load16(const void* g, void* l) {
    __builtin_amdgcn_global_load_lds(
        (const __attribute__((address_space(1))) void*)g,
        (__attribute__((address_space(3))) void*)l,
        16, 0, 0);
}

// ---------------- prepass 1: x fp32 -> fp16 (lossless; values are fp16) -----
__global__ __launch_bounds__(256) void convert_x(
    const float* __restrict__ x, _Float16* __restrict__ x16)
{
    const size_t i = ((size_t)blockIdx.x * 256 + threadIdx.x) * 8;
    float4 a = *(const float4*)(x + i);
    float4 b = *(const float4*)(x + i + 4);
    half8 h;
    h[0] = (_Float16)a.x; h[1] = (_Float16)a.y; h[2] = (_Float16)a.z; h[3] = (_Float16)a.w;
    h[4] = (_Float16)b.x; h[5] = (_Float16)b.y; h[6] = (_Float16)b.z; h[7] = (_Float16)b.w;
    *(half8*)(x16 + i) = h;
}

// ------------- prepass 2: dequant packed ternary -> fp16 W^T (N x K) --------
// code c in {0,1,2} -> w*s in {-s,0,+s}, selected exactly via v_perm_b32 from
// template bytes [0]=lo(s) [1]=hi(+s) [2]=0x00 [3]=hi(-s)  (s > 0).
__global__ __launch_bounds__(256) void dequant_w(
    const int* __restrict__ pw, const float* __restrict__ scales,
    _Float16* __restrict__ w16t)
{
    const int kp = (int)(blockIdx.x * 16) + (int)(threadIdx.x & 15);   // 0..255
    const int n  = (int)(blockIdx.y * 16) + (int)(threadIdx.x >> 4);   // 0..11007

    uint32_t v  = (uint32_t)pw[(size_t)kp * N_DIM + n];
    _Float16 sh = (_Float16)scales[(size_t)(kp >> 3) * N_DIM + n];     // lossless
    uint32_t sbits = (uint32_t)__builtin_bit_cast(unsigned short, sh);
    uint32_t tmpl  = sbits | (((sbits >> 8) ^ 0x80u) << 24);

    uint32_t q[8];
    #pragma unroll
    for (int j = 0; j < 8; ++j) {
        uint32_t t4 = (v >> (4 * j)) & 0xFu;             // c0 @bits1:0, c1 @bits3:2
        uint32_t sp = (t4 | (t4 << 14)) & 0x00030003u;   // c0 @byte0, c1 @byte2
        uint32_t sel = ((sp & 0x00010001u) << 1) | ((0x00030003u - sp) << 8);
        q[j] = __builtin_amdgcn_perm(tmpl, tmpl, sel);
    }
    _Float16* dst = w16t + (size_t)n * K_DIM + (size_t)kp * 16;
    *(uint4*)(dst)     = make_uint4(q[0], q[1], q[2], q[3]);
    *(uint4*)(dst + 8) = make_uint4(q[4], q[5], q[6], q[7]);
}

// ---------------- main GEMM: m97 structure, A and B via global_load_lds -----
__global__ __launch_bounds__(256, 2) void gemm_f16(
    const _Float16* __restrict__ x16,   // (M, K)
    const _Float16* __restrict__ w16t,  // (N, K)
    const float*    __restrict__ bias,  // (N,)
    float*          __restrict__ out)   // (M, N)
{
    __shared__ __align__(16) _Float16 lds_a[BM * BK];   // [m][k], stride 32 (DMA layout)
    __shared__ __align__(16) _Float16 lds_b[BN * BK];   // [n][k], stride 32 (DMA layout)

    const int tid  = threadIdx.x;
    const int lane = tid & 63;
    const int wave = tid >> 6;

    const int n0 = blockIdx.x * BN;
    const int m0 = blockIdx.y * BM;

    const int wm = (wave & 1) * 64;
    const int wn = (wave >> 1) * 64;

    // staging: lane-linear 16 B/lane; 4 lanes x 8 halves = one 32-half row
    const int sr = tid >> 2;            // row 0..63 (+64 on second issue)
    const int sk = (tid & 3) * 8;
    const _Float16* ag0 = x16  + (size_t)(m0 + sr) * K_DIM + sk;
    const _Float16* ag1 = ag0 + (size_t)64 * K_DIM;
    const _Float16* bg0 = w16t + (size_t)(n0 + sr) * K_DIM + sk;
    const _Float16* bg1 = bg0 + (size_t)64 * K_DIM;
    _Float16* al = lds_a + tid * 8;
    _Float16* blp = lds_b + tid * 8;

    floatx4 acc[4][4];
    #pragma unroll
    for (int i = 0; i < 4; ++i)
        #pragma unroll
        for (int j = 0; j < 4; ++j)
            acc[i][j] = floatx4{0.f, 0.f, 0.f, 0.f};

    const int lr = lane & 15;
    const int qk = (lane >> 4) * 8;

    for (int slab = 0; slab < NSLAB; ++slab) {
        const size_t ko = (size_t)slab * BK;
        async_load16(ag0 + ko, al);
        async_load16(ag1 + ko, al + 2048);
        async_load16(bg0 + ko, blp);
        async_load16(bg1 + ko, blp + 2048);

        __syncthreads();   // drains vmcnt (DMA arrival)

        half8 af[4], bf[4];
        #pragma unroll
        for (int t = 0; t < 4; ++t) {
            af[t] = *(const half8*)&lds_a[(wm + t * 16 + lr) * BK + qk];
            bf[t] = *(const half8*)&lds_b[(wn + t * 16 + lr) * BK + qk];
        }
        #pragma unroll
        for (int mt = 0; mt < 4; ++mt)
            #pragma unroll
            for (int nt = 0; nt < 4; ++nt)
                acc[mt][nt] = __builtin_amdgcn_mfma_f32_16x16x32_f16(
                    af[mt], bf[nt], acc[mt][nt], 0, 0, 0);

        __syncthreads();
    }

    float bv[4];
    #pragma unroll
    for (int nt = 0; nt < 4; ++nt) bv[nt] = bias[n0 + wn + nt * 16 + lr];

    const int rbase = (lane >> 4) * 4;  // C layout: row = (lane>>4)*4 + reg
    #pragma unroll
    for (int mt = 0; mt < 4; ++mt) {
        #pragma unroll
        for (int nt = 0; nt < 4; ++nt) {
            const int col = n0 + wn + nt * 16 + lr;
            float* op = out + (size_t)(m0 + wm + mt * 16 + rbase) * N_DIM + col;
            floatx4 a = acc[mt][nt];
            #pragma unroll
            for (int r = 0; r < 4; ++r)
                op[(size_t)r * N_DIM] = a[r] + bv[nt];
        }
    }
}

// ---------------- fallback: round-3 fused kernel (ws too small) -------------
#define ASTRIDE 40
#define BSTRIDE 40
__global__ __launch_bounds__(256, 2) void ternary_gemm_fused(
    const float* __restrict__ x, const int* __restrict__ pw,
    const float* __restrict__ scales, const float* __restrict__ bias,
    float* __restrict__ out)
{
    __shared__ __align__(16) _Float16 lds_a[BM * ASTRIDE];
    __shared__ __align__(16) _Float16 lds_b[BN * BSTRIDE];

    const int tid  = threadIdx.x;
    const int lane = tid & 63;
    const int wave = tid >> 6;
    const int n0 = blockIdx.x * BN;
    const int m0 = blockIdx.y * BM;
    const int wm = (wave & 1) * 64;
    const int wn = (wave >> 1) * 64;

    const int nb  = tid & 127;
    const int kpi = tid >> 7;
    const int*   pwp = pw + (size_t)kpi * N_DIM + n0 + nb;
    const float* scp = scales + n0 + nb;
    _Float16* bl = lds_b + nb * BSTRIDE + kpi * 16;

    floatx4 acc[4][4];
    #pragma unroll
    for (int i = 0; i < 4; ++i)
        #pragma unroll
        for (int j = 0; j < 4; ++j)
            acc[i][j] = floatx4{0.f, 0.f, 0.f, 0.f};

    const int lr = lane & 15;
    const int qk = (lane >> 4) * 8;

    for (int slab = 0; slab < NSLAB; ++slab) {
        const int k0 = slab * BK;
        #pragma unroll
        for (int i = 0; i < 4; ++i) {
            const int idx = tid + i * 256;
            const int row = idx >> 3;
            const int kq  = (idx & 7) * 4;
            float4 v4 = *(const float4*)(x + (size_t)(m0 + row) * K_DIM + k0 + kq);
            half2v h0; h0[0] = (_Float16)v4.x; h0[1] = (_Float16)v4.y;
            half2v h1; h1[0] = (_Float16)v4.z; h1[1] = (_Float16)v4.w;
            *(uint2*)(lds_a + row * ASTRIDE + kq) =
                make_uint2(__builtin_bit_cast(uint32_t, h0),
                           __builtin_bit_cast(uint32_t, h1));
        }
        uint32_t v  = (uint32_t)pwp[(size_t)slab * 2 * N_DIM];
        _Float16 sh = (_Float16)scp[(size_t)(slab >> 2) * N_DIM];
        uint32_t sbits = (uint32_t)__builtin_bit_cast(unsigned short, sh);
        uint32_t tmpl = sbits | (((sbits >> 8) ^ 0x80u) << 24);
        uint32_t q[8];
        #pragma unroll
        for (int j = 0; j < 8; ++j) {
            uint32_t t4 = (v >> (4 * j)) & 0xFu;
            uint32_t sp = (t4 | (t4 << 14)) & 0x00030003u;
            uint32_t sel = ((sp & 0x00010001u) << 1) | ((0x00030003u - sp) << 8);
            q[j] = __builtin_amdgcn_perm(tmpl, tmpl, sel);
        }
        *(uint4*)(bl)     = make_uint4(q[0], q[1], q[2], q[3]);
        *(uint4*)(bl + 8) = make_uint4(q[4], q[5], q[6], q[7]);

        __syncthreads();

        half8 af[4], bfr[4];
        #pragma unroll
        for (int t = 0; t < 4; ++t) {
            af[t]  = *(const half8*)&lds_a[(wm + t * 16 + lr) * ASTRIDE + qk];
            bfr[t] = *(const half8*)&lds_b[(wn + t * 16 + lr) * BSTRIDE + qk];
        }
        #pragma unroll
        for (int mt = 0; mt < 4; ++mt)
            #pragma unroll
            for (int nt = 0; nt < 4; ++nt)
                acc[mt][nt] = __builtin_amdgcn_mfma_f32_16x16x32_f16(
                    af[mt], bfr[nt], acc[mt][nt], 0, 0, 0);

        __syncthreads();
    }

    float bv[4];
    #pragma unroll
    for (int nt = 0; nt < 4; ++nt) bv[nt] = bias[n0 + wn + nt * 16 + lr];
    const int rbase = (lane >> 4) * 4;
    #pragma unroll
    for (int mt = 0; mt < 4; ++mt) {
        #pragma unroll
        for (int nt = 0; nt < 4; ++nt) {
            const int col = n0 + wn + nt * 16 + lr;
            float* op = out + (size_t)(m0 + wm + mt * 16 + rbase) * N_DIM + col;
            floatx4 a = acc[mt][nt];
            #pragma unroll
            for (int r = 0; r < 4; ++r)
                op[(size_t)r * N_DIM] = a[r] + bv[nt];
        }
    }
}

extern "C" void kernel_launch(void* const* d_in, const int* in_sizes, int n_in,
                              void* d_out, int out_size, void* d_ws, size_t ws_size,
                              hipStream_t stream) {
    const float* x  = (const float*)d_in[0];
    const int*   pw = (const int*)d_in[1];
    const float* sc = (const float*)d_in[2];
    const float* bs = (const float*)d_in[3];
    float* out = (float*)d_out;

    dim3 grid(N_DIM / BN, M_DIM / BM);   // 86 x 64 = 5504 blocks

    if (ws_size >= WS_NEEDED) {
        _Float16* x16  = (_Float16*)d_ws;
        _Float16* w16t = (_Float16*)((char*)d_ws + WS_X16_BYTES);
        convert_x<<<(M_DIM * (size_t)K_DIM) / (8 * 256), 256, 0, stream>>>(x, x16);
        dim3 dq_grid((K_DIM / 16) / 16, N_DIM / 16);   // (16, 688)
        dequant_w<<<dq_grid, 256, 0, stream>>>(pw, sc, w16t);
        gemm_f16<<<grid, 256, 0, stream>>>(x16, w16t, bs, out);
    } else {
        ternary_gemm_fused<<<grid, 256, 0, stream>>>(x, pw, sc, bs, out);
    }
}